// Round 7
// baseline (187.807 us; speedup 1.0000x reference)
//
#include <hip/hip_runtime.h>
#include <hip/hip_bf16.h>
#include <math.h>

#define S_LEN 2048
#define BATCH 4
#define HDIM 768
#define LOUT 9
#define NROWS (BATCH*S_LEN)
#define K2H 1536
#define WIN 11
#define NEG_INF_F (-1e30f)

typedef __attribute__((ext_vector_type(4))) float f32x4;
typedef __attribute__((ext_vector_type(8))) short bf16x8;

static __device__ __forceinline__ void async_ld16(const void* g, void* l) {
  __builtin_amdgcn_global_load_lds((const __attribute__((address_space(1))) void*)g,
                                   (__attribute__((address_space(3))) void*)l, 16, 0, 0);
}

static __device__ __forceinline__ unsigned short f2bf(float f) {
  union { float f; unsigned int u; } v; v.f = f;
  unsigned int u = v.u;
  unsigned int r = (u + 0x7fffu + ((u >> 16) & 1u)) >> 16;
  return (unsigned short)r;
}

static __device__ __forceinline__ float bf2f(unsigned short h) {
  union { unsigned int u; float f; } v; v.u = ((unsigned int)h) << 16;
  return v.f;
}

// Kernel 1: W1 [1536][768] fp32 -> W1t [768][1536] bf16 (LDS-tiled transpose)
__global__ __launch_bounds__(256) void k_prep_w1t(const float* __restrict__ W1,
                                                  unsigned short* __restrict__ W1t) {
  __shared__ float tile[32][33];
  int bk = blockIdx.x % 48;
  int bn = blockIdx.x / 48;
  int tc = threadIdx.x % 32;
  int tr = threadIdx.x / 32;
  #pragma unroll
  for (int i = 0; i < 32; i += 8) {
    tile[tr + i][tc] = W1[(bk*32 + tr + i) * HDIM + bn*32 + tc];
  }
  __syncthreads();
  #pragma unroll
  for (int i = 0; i < 32; i += 8) {
    W1t[(bn*32 + tr + i) * K2H + bk*32 + tc] = f2bf(tile[tc][tr + i]);
  }
}

// Kernel 2: one pass over fp32 x per row —
//   x -> bf16 first half of xc, score = x·wa+ba, base logits = x·Wc+bc.
__global__ __launch_bounds__(192) void k_prep(const float* __restrict__ x,
                                              const float* __restrict__ wa,
                                              const float* __restrict__ ba,
                                              const float* __restrict__ Wc,
                                              const float* __restrict__ bc,
                                              unsigned short* __restrict__ xc,
                                              float* __restrict__ scores,
                                              float* __restrict__ base) {
  __shared__ float red[3][LOUT + 1];
  int bid = blockIdx.x;
  int row = (bid & 7) * 1024 + (bid >> 3);
  int t = threadIdx.x;
  int lane = t & 63, wave = t >> 6;
  const float4 v = *(const float4*)(x + row * HDIM + t * 4);
  const float4 w = *(const float4*)(wa + t * 4);
  ushort4 o;
  o.x = f2bf(v.x); o.y = f2bf(v.y); o.z = f2bf(v.z); o.w = f2bf(v.w);
  *(ushort4*)(xc + row * K2H + t * 4) = o;

  float pv[LOUT + 1];
  pv[LOUT] = v.x * w.x + v.y * w.y + v.z * w.z + v.w * w.w;
  #pragma unroll
  for (int l = 0; l < LOUT; ++l) pv[l] = 0.f;
  const float xvv[4] = { v.x, v.y, v.z, v.w };
  #pragma unroll
  for (int j = 0; j < 4; ++j) {
    const float* wr = Wc + (t * 4 + j) * LOUT;
    #pragma unroll
    for (int l = 0; l < LOUT; ++l) pv[l] += xvv[j] * wr[l];
  }
  #pragma unroll
  for (int l = 0; l <= LOUT; ++l)
    #pragma unroll
    for (int m = 1; m < 64; m <<= 1) pv[l] += __shfl_xor(pv[l], m);
  if (lane == 0) {
    #pragma unroll
    for (int l = 0; l <= LOUT; ++l) red[wave][l] = pv[l];
  }
  __syncthreads();
  if (t < LOUT) {
    base[row * LOUT + t] = red[0][t] + red[1][t] + red[2][t] + bc[t];
  } else if (t == LOUT) {
    scores[row] = red[0][LOUT] + red[1][LOUT] + red[2][LOUT] + ba[0];
  }
}

// Kernel 3: window softmax (scores precomputed) + weighted ctx from bf16 xc
__global__ __launch_bounds__(192) void k_ctx(const float* __restrict__ scores,
                                             unsigned short* __restrict__ xc) {
  __shared__ float swin[WIN];
  int bid = blockIdx.x;
  int row = (bid & 7) * 1024 + (bid >> 3);
  int b = row >> 11, s = row & 2047;
  int t = threadIdx.x;
  if (t < WIN) {
    int j = s - 5 + t;
    bool valid = (j >= 0) && (j < S_LEN);
    int jc = valid ? j : (j < 0 ? 0 : S_LEN - 1);
    swin[t] = valid ? scores[b * S_LEN + jc] : NEG_INF_F;
  }
  __syncthreads();
  float mx = swin[0];
  #pragma unroll
  for (int w = 1; w < WIN; ++w) mx = fmaxf(mx, swin[w]);
  float es[WIN], ssum = 0.f;
  #pragma unroll
  for (int w = 0; w < WIN; ++w) {
    float sv = swin[w];
    es[w] = (sv > -1e29f) ? __expf(sv - mx) : 0.f;
    ssum += es[w];
  }
  float inv = 1.f / ssum;
  float c0 = 0.f, c1 = 0.f, c2 = 0.f, c3 = 0.f;
  #pragma unroll
  for (int w = 0; w < WIN; ++w) {
    float aw = es[w] * inv;
    int j = s - 5 + w;
    int jc = (j < 0) ? 0 : ((j >= S_LEN) ? S_LEN - 1 : j);
    const ushort4 uv = *(const ushort4*)(xc + (((long)b * S_LEN + jc) * K2H) + t * 4);
    c0 += aw * bf2f(uv.x);
    c1 += aw * bf2f(uv.y);
    c2 += aw * bf2f(uv.z);
    c3 += aw * bf2f(uv.w);
  }
  ushort4 o;
  o.x = f2bf(c0); o.y = f2bf(c1); o.z = f2bf(c2); o.w = f2bf(c3);
  *(ushort4*)(xc + row * K2H + HDIM + t * 4) = o;
}

// Kernel 4: h = xc(bf16,[8192][1536]) @ W1t^T + b1 -> BF16 [8192][768]
// 128x64 tile, BK=64 (24 iters, 16 MFMA/wave/iter), ring-3 LDS (72 KB,
// 2 blocks/CU), depth-2 counted-vmcnt prefetch, 8-slot XOR swizzle
// (both-sides: pre-swizzled global source + swizzled ds_read).
__global__ __launch_bounds__(256, 2) void k_gemm(const unsigned short* __restrict__ A,
                                                 const unsigned short* __restrict__ Bt,
                                                 const float* __restrict__ b1,
                                                 unsigned short* __restrict__ Hout) {
  __shared__ unsigned short As[3][128 * 64];  // 16 KB x3
  __shared__ unsigned short Bs[3][64 * 64];   // 8 KB x3
  int bid = blockIdx.x;
  int obid = (bid & 7) * 96 + (bid >> 3);     // XCD swizzle (768%8==0, bijective)
  int bm = obid / 12, bn = obid % 12;
  int t = threadIdx.x;
  int lane = t & 63, wave = t >> 6;

  // --- staging geometry: per call a wave writes 8 rows x 128B (1 KB) ---
  // lane -> row_in_chunk = lane>>3, slot = lane&7 (16B units in a 128B row).
  // swizzle: physical slot p of tile-row r holds global slot p ^ f(r),
  // f(r) = (r ^ (r>>3)) & 7. Achieved by pre-swizzling the SOURCE slot.
  int rowc = lane >> 3;          // 0..7
  int slot = lane & 7;
  // A: 4 chunks (j=0..3), tile row = j*32 + wave*8 + rowc
  const unsigned short* gAj[4];
  #pragma unroll
  for (int j = 0; j < 4; ++j) {
    int rloc = j * 32 + wave * 8 + rowc;
    int f = (rloc ^ (rloc >> 3)) & 7;
    gAj[j] = A + (bm * 128 + rloc) * K2H + ((slot ^ f) & 7) * 8;
  }
  // B: 2 chunks (j=0..1), tile row = j*32 + wave*8 + rowc
  const unsigned short* gBj[2];
  #pragma unroll
  for (int j = 0; j < 2; ++j) {
    int rloc = j * 32 + wave * 8 + rowc;
    int f = (rloc ^ (rloc >> 3)) & 7;
    gBj[j] = Bt + (bn * 64 + rloc) * K2H + ((slot ^ f) & 7) * 8;
  }

  f32x4 acc[2][4] = {};

#define STAGE(buf, kt) do {                                                    \
    _Pragma("unroll")                                                          \
    for (int j = 0; j < 4; ++j)                                                \
      async_ld16(gAj[j] + (kt), &As[buf][(j * 32 + wave * 8) * 64]);           \
    _Pragma("unroll")                                                          \
    for (int j = 0; j < 2; ++j)                                                \
      async_ld16(gBj[j] + (kt), &Bs[buf][(j * 32 + wave * 8) * 64]);           \
  } while (0)

#define COMPUTE(buf) do {                                                      \
    const unsigned short* aB = &As[buf][0];                                    \
    const unsigned short* bB = &Bs[buf][0];                                    \
    _Pragma("unroll")                                                          \
    for (int kk = 0; kk < 2; ++kk) {                                           \
      bf16x8 af[2], bfv[4];                                                    \
      _Pragma("unroll")                                                        \
      for (int m = 0; m < 2; ++m) {                                            \
        int rl = wave * 32 + m * 16 + (lane & 15);                             \
        int f = (rl ^ (rl >> 3)) & 7;                                          \
        int sl = (kk * 4 + (lane >> 4)) ^ f;                                   \
        af[m] = *(const bf16x8*)(aB + rl * 64 + sl * 8);                       \
      }                                                                        \
      _Pragma("unroll")                                                        \
      for (int n = 0; n < 4; ++n) {                                            \
        int rl = n * 16 + (lane & 15);                                         \
        int f = (rl ^ (rl >> 3)) & 7;                                          \
        int sl = (kk * 4 + (lane >> 4)) ^ f;                                   \
        bfv[n] = *(const bf16x8*)(bB + rl * 64 + sl * 8);                      \
      }                                                                        \
      _Pragma("unroll")                                                        \
      for (int m = 0; m < 2; ++m)                                              \
        _Pragma("unroll")                                                      \
        for (int n = 0; n < 4; ++n)                                            \
          acc[m][n] = __builtin_amdgcn_mfma_f32_16x16x32_bf16(af[m], bfv[n], acc[m][n], 0, 0, 0); \
    }                                                                          \
  } while (0)

#define WBAR(n) asm volatile("s_waitcnt vmcnt(" #n ")\n\ts_barrier" ::: "memory")

  // prologue: stage tiles 0,1 (12 loads/thread in flight)
  STAGE(0, 0);
  STAGE(1, 64);

  // main loop: compute tiles 0..21, staging tile tt+2 each iter.
  int bufc = 0;
  for (int tt = 0; tt < 22; ++tt) {
    WBAR(6);                         // tile tt landed; tile tt+1 in flight
    int bufn = bufc + 2; if (bufn >= 3) bufn -= 3;
    STAGE(bufn, (tt + 2) * 64);
    COMPUTE(bufc);
    bufc = (bufc == 2) ? 0 : bufc + 1;
  }
  WBAR(6);  COMPUTE(bufc);           // tile 22 (buf 1)
  bufc = (bufc == 2) ? 0 : bufc + 1;
  WBAR(0);  COMPUTE(bufc);           // tile 23 (buf 2)

  // epilogue: + b1, cast bf16, store
  int orow = bm * 128 + wave * 32 + (lane >> 4) * 4;
  int ocol = bn * 64 + (lane & 15);
  #pragma unroll
  for (int m = 0; m < 2; ++m)
    #pragma unroll
    for (int n = 0; n < 4; ++n) {
      int col = ocol + n * 16;
      float bv = b1[col];
      #pragma unroll
      for (int r = 0; r < 4; ++r) {
        Hout[(orow + m * 16 + r) * HDIM + col] = f2bf(acc[m][n][r] + bv);
      }
    }
#undef STAGE
#undef COMPUTE
#undef WBAR
}

// Kernel 5: LayerNorm + exact GELU + W2 matvec (9) + 0.5/0.5 combine with base
// h is bf16 now; 192 threads, ushort4 per thread.
__global__ __launch_bounds__(192) void k_ln(const unsigned short* __restrict__ Hin,
                                            const float* __restrict__ gamma,
                                            const float* __restrict__ beta,
                                            const float* __restrict__ W2,
                                            const float* __restrict__ b2,
                                            const float* __restrict__ base,
                                            float* __restrict__ out) {
  __shared__ float redS[3], redQ[3], redp[3][LOUT];
  int row = blockIdx.x;
  int t = threadIdx.x;
  int lane = t & 63, wave = t >> 6;
  const ushort4 hv = *(const ushort4*)(Hin + row * HDIM + t * 4);
  const float vv[4] = { bf2f(hv.x), bf2f(hv.y), bf2f(hv.z), bf2f(hv.w) };
  float s1 = vv[0] + vv[1] + vv[2] + vv[3];
  float s2 = vv[0]*vv[0] + vv[1]*vv[1] + vv[2]*vv[2] + vv[3]*vv[3];
  #pragma unroll
  for (int m = 1; m < 64; m <<= 1) { s1 += __shfl_xor(s1, m); s2 += __shfl_xor(s2, m); }
  if (lane == 0) { redS[wave] = s1; redQ[wave] = s2; }
  __syncthreads();
  s1 = redS[0] + redS[1] + redS[2];
  s2 = redQ[0] + redQ[1] + redQ[2];
  float mu = s1 * (1.f / HDIM);
  float var = s2 * (1.f / HDIM) - mu * mu;
  float rstd = rsqrtf(var + 1e-5f);
  const float4 g4 = *(const float4*)(gamma + t * 4);
  const float4 be4 = *(const float4*)(beta + t * 4);
  const float gv[4] = { g4.x, g4.y, g4.z, g4.w };
  const float bv[4] = { be4.x, be4.y, be4.z, be4.w };
  float p[LOUT] = {};
  #pragma unroll
  for (int j = 0; j < 4; ++j) {
    float g = (vv[j] - mu) * rstd * gv[j] + bv[j];
    float gg = 0.5f * g * (1.f + erff(g * 0.70710678118654752f));
    const float* wrow = W2 + (t * 4 + j) * LOUT;
    #pragma unroll
    for (int l = 0; l < LOUT; ++l) p[l] += gg * wrow[l];
  }
  #pragma unroll
  for (int l = 0; l < LOUT; ++l)
    #pragma unroll
    for (int m = 1; m < 64; m <<= 1) p[l] += __shfl_xor(p[l], m);
  if (lane == 0) {
    #pragma unroll
    for (int l = 0; l < LOUT; ++l) redp[wave][l] = p[l];
  }
  __syncthreads();
  if (t < LOUT) {
    float cl = redp[0][t] + redp[1][t] + redp[2][t] + b2[t];
    out[row * LOUT + t] = 0.5f * base[row * LOUT + t] + 0.5f * cl;
  }
}

extern "C" void kernel_launch(void* const* d_in, const int* in_sizes, int n_in,
                              void* d_out, int out_size, void* d_ws, size_t ws_size,
                              hipStream_t stream) {
  const float* x     = (const float*)d_in[0];
  const float* Wc    = (const float*)d_in[1];
  const float* bc    = (const float*)d_in[2];
  const float* wa    = (const float*)d_in[3];
  const float* ba    = (const float*)d_in[4];
  const float* W1    = (const float*)d_in[5];
  const float* b1    = (const float*)d_in[6];
  const float* gamma = (const float*)d_in[7];
  const float* beta  = (const float*)d_in[8];
  const float* W2    = (const float*)d_in[9];
  const float* b2    = (const float*)d_in[10];
  float* out = (float*)d_out;

  char* ws = (char*)d_ws;
  unsigned short* xc  = (unsigned short*)(ws);             // 8192*1536*2  = 25,165,824
  unsigned short* w1t = (unsigned short*)(ws + 25165824);  // 768*1536*2   =  2,359,296
  float* scores       = (float*)(ws + 27525120);           // 8192*4       =     32,768
  float* base         = (float*)(ws + 27557888);           // 8192*9*4     =    294,912
  unsigned short* hbuf = (unsigned short*)(ws + 27852800); // 8192*768*2   = 12,582,912

  k_prep_w1t<<<dim3(1152), dim3(256), 0, stream>>>(W1, w1t);
  k_prep    <<<dim3(8192), dim3(192), 0, stream>>>(x, wa, ba, Wc, bc, xc, scores, base);
  k_ctx     <<<dim3(8192), dim3(192), 0, stream>>>(scores, xc);
  k_gemm    <<<dim3(768),  dim3(256), 0, stream>>>(xc, w1t, b1, hbuf);
  k_ln      <<<dim3(8192), dim3(192), 0, stream>>>(hbuf, gamma, beta, W2, b2, base, out);
}

// Round 8
// 185.295 us; speedup vs baseline: 1.0136x; 1.0136x over previous
//
#include <hip/hip_runtime.h>
#include <hip/hip_bf16.h>
#include <math.h>

#define S_LEN 2048
#define BATCH 4
#define HDIM 768
#define LOUT 9
#define NROWS (BATCH*S_LEN)
#define K2H 1536
#define WIN 11
#define NEG_INF_F (-1e30f)

typedef __attribute__((ext_vector_type(4))) float f32x4;
typedef __attribute__((ext_vector_type(8))) short bf16x8;

static __device__ __forceinline__ void async_ld16(const void* g, void* l) {
  __builtin_amdgcn_global_load_lds((const __attribute__((address_space(1))) void*)g,
                                   (__attribute__((address_space(3))) void*)l, 16, 0, 0);
}

static __device__ __forceinline__ unsigned short f2bf(float f) {
  union { float f; unsigned int u; } v; v.f = f;
  unsigned int u = v.u;
  unsigned int r = (u + 0x7fffu + ((u >> 16) & 1u)) >> 16;
  return (unsigned short)r;
}

static __device__ __forceinline__ float bf2f(unsigned short h) {
  union { unsigned int u; float f; } v; v.u = ((unsigned int)h) << 16;
  return v.f;
}

// Kernel 1: W1 [1536][768] fp32 -> W1t [768][1536] bf16 (LDS-tiled transpose)
__global__ __launch_bounds__(256) void k_prep_w1t(const float* __restrict__ W1,
                                                  unsigned short* __restrict__ W1t) {
  __shared__ float tile[32][33];
  int bk = blockIdx.x % 48;
  int bn = blockIdx.x / 48;
  int tc = threadIdx.x % 32;
  int tr = threadIdx.x / 32;
  #pragma unroll
  for (int i = 0; i < 32; i += 8) {
    tile[tr + i][tc] = W1[(bk*32 + tr + i) * HDIM + bn*32 + tc];
  }
  __syncthreads();
  #pragma unroll
  for (int i = 0; i < 32; i += 8) {
    W1t[(bn*32 + tr + i) * K2H + bk*32 + tc] = f2bf(tile[tc][tr + i]);
  }
}

// Kernel 2: one pass over fp32 x per row —
//   x -> bf16 first half of xc, score = x·wa+ba, base logits = x·Wc+bc.
__global__ __launch_bounds__(192) void k_prep(const float* __restrict__ x,
                                              const float* __restrict__ wa,
                                              const float* __restrict__ ba,
                                              const float* __restrict__ Wc,
                                              const float* __restrict__ bc,
                                              unsigned short* __restrict__ xc,
                                              float* __restrict__ scores,
                                              float* __restrict__ base) {
  __shared__ float red[3][LOUT + 1];
  int bid = blockIdx.x;
  int row = (bid & 7) * 1024 + (bid >> 3);
  int t = threadIdx.x;
  int lane = t & 63, wave = t >> 6;
  const float4 v = *(const float4*)(x + row * HDIM + t * 4);
  const float4 w = *(const float4*)(wa + t * 4);
  ushort4 o;
  o.x = f2bf(v.x); o.y = f2bf(v.y); o.z = f2bf(v.z); o.w = f2bf(v.w);
  *(ushort4*)(xc + row * K2H + t * 4) = o;

  float pv[LOUT + 1];
  pv[LOUT] = v.x * w.x + v.y * w.y + v.z * w.z + v.w * w.w;
  #pragma unroll
  for (int l = 0; l < LOUT; ++l) pv[l] = 0.f;
  const float xvv[4] = { v.x, v.y, v.z, v.w };
  #pragma unroll
  for (int j = 0; j < 4; ++j) {
    const float* wr = Wc + (t * 4 + j) * LOUT;
    #pragma unroll
    for (int l = 0; l < LOUT; ++l) pv[l] += xvv[j] * wr[l];
  }
  #pragma unroll
  for (int l = 0; l <= LOUT; ++l)
    #pragma unroll
    for (int m = 1; m < 64; m <<= 1) pv[l] += __shfl_xor(pv[l], m);
  if (lane == 0) {
    #pragma unroll
    for (int l = 0; l <= LOUT; ++l) red[wave][l] = pv[l];
  }
  __syncthreads();
  if (t < LOUT) {
    base[row * LOUT + t] = red[0][t] + red[1][t] + red[2][t] + bc[t];
  } else if (t == LOUT) {
    scores[row] = red[0][LOUT] + red[1][LOUT] + red[2][LOUT] + ba[0];
  }
}

// Kernel 3: window softmax (scores precomputed) + weighted ctx from bf16 xc
__global__ __launch_bounds__(192) void k_ctx(const float* __restrict__ scores,
                                             unsigned short* __restrict__ xc) {
  __shared__ float swin[WIN];
  int bid = blockIdx.x;
  int row = (bid & 7) * 1024 + (bid >> 3);
  int b = row >> 11, s = row & 2047;
  int t = threadIdx.x;
  if (t < WIN) {
    int j = s - 5 + t;
    bool valid = (j >= 0) && (j < S_LEN);
    int jc = valid ? j : (j < 0 ? 0 : S_LEN - 1);
    swin[t] = valid ? scores[b * S_LEN + jc] : NEG_INF_F;
  }
  __syncthreads();
  float mx = swin[0];
  #pragma unroll
  for (int w = 1; w < WIN; ++w) mx = fmaxf(mx, swin[w]);
  float es[WIN], ssum = 0.f;
  #pragma unroll
  for (int w = 0; w < WIN; ++w) {
    float sv = swin[w];
    es[w] = (sv > -1e29f) ? __expf(sv - mx) : 0.f;
    ssum += es[w];
  }
  float inv = 1.f / ssum;
  float c0 = 0.f, c1 = 0.f, c2 = 0.f, c3 = 0.f;
  #pragma unroll
  for (int w = 0; w < WIN; ++w) {
    float aw = es[w] * inv;
    int j = s - 5 + w;
    int jc = (j < 0) ? 0 : ((j >= S_LEN) ? S_LEN - 1 : j);
    const ushort4 uv = *(const ushort4*)(xc + (((long)b * S_LEN + jc) * K2H) + t * 4);
    c0 += aw * bf2f(uv.x);
    c1 += aw * bf2f(uv.y);
    c2 += aw * bf2f(uv.z);
    c3 += aw * bf2f(uv.w);
  }
  ushort4 o;
  o.x = f2bf(c0); o.y = f2bf(c1); o.z = f2bf(c2); o.w = f2bf(c3);
  *(ushort4*)(xc + row * K2H + HDIM + t * 4) = o;
}

// Kernel 4: h = xc(bf16,[8192][1536]) @ W1t^T + b1 -> BF16 [8192][768]
// MAX-TLP: 64x64 tile, BK=32, ring-3 LDS = 24 KB -> 6 blocks/CU, whole grid
// (1536 blocks) co-resident. Counted vmcnt(2), stage-after-barrier (ring-3
// makes prefetch hazard-free). 4 waves, each 32x32 out. XOR slot swizzle.
__global__ __launch_bounds__(256, 6) void k_gemm(const unsigned short* __restrict__ A,
                                                 const unsigned short* __restrict__ Bt,
                                                 const float* __restrict__ b1,
                                                 unsigned short* __restrict__ Hout) {
  __shared__ unsigned short As[3][64 * 32];  // 4 KB x3
  __shared__ unsigned short Bs[3][64 * 32];  // 4 KB x3   -> 24 KB total
  int bid = blockIdx.x;
  int obid = (bid & 7) * 192 + (bid >> 3);   // XCD swizzle (1536%8==0, bijective)
  int bm = obid / 12, bn = obid % 12;
  int t = threadIdx.x;
  int lane = t & 63, wave = t >> 6;
  int wm = wave >> 1, wn = wave & 1;

  // --- staging: one 16B load per thread per matrix per K-tile ---
  // wave covers rows [wave*16, wave*16+16); lane -> row wave*16+(lane>>2),
  // slot lane&3. Source slot pre-swizzled: phys slot p of row r holds
  // global slot p ^ f(r), f(r)=(r^(r>>2))&3  (rule #21: both-sides).
  int rST = wave * 16 + (lane >> 2);
  int fST = (rST ^ (rST >> 2)) & 3;
  int sST = ((lane & 3) ^ fST) & 3;
  const unsigned short* gA = A  + (bm * 64 + rST) * K2H + sST * 8;
  const unsigned short* gB = Bt + (bn * 64 + rST) * K2H + sST * 8;

  // --- read offsets (element units), precomputed ---
  int aoff[2], boff[2];
  #pragma unroll
  for (int m = 0; m < 2; ++m) {
    int rl = wm * 32 + m * 16 + (lane & 15);
    int f = (rl ^ (rl >> 2)) & 3;
    aoff[m] = rl * 32 + (((lane >> 4) ^ f) & 3) * 8;
  }
  #pragma unroll
  for (int n = 0; n < 2; ++n) {
    int rl = wn * 32 + n * 16 + (lane & 15);
    int f = (rl ^ (rl >> 2)) & 3;
    boff[n] = rl * 32 + (((lane >> 4) ^ f) & 3) * 8;
  }

  f32x4 acc[2][2] = {};

#define STAGE(buf, kt) do {                                                    \
    async_ld16(gA + (kt), &As[buf][wave * 512]);                               \
    async_ld16(gB + (kt), &Bs[buf][wave * 512]);                               \
  } while (0)

#define COMPUTE(buf) do {                                                      \
    bf16x8 af[2], bfv[2];                                                      \
    af[0] = *(const bf16x8*)(&As[buf][aoff[0]]);                               \
    af[1] = *(const bf16x8*)(&As[buf][aoff[1]]);                               \
    bfv[0] = *(const bf16x8*)(&Bs[buf][boff[0]]);                              \
    bfv[1] = *(const bf16x8*)(&Bs[buf][boff[1]]);                              \
    _Pragma("unroll")                                                          \
    for (int m = 0; m < 2; ++m)                                                \
      _Pragma("unroll")                                                        \
      for (int n = 0; n < 2; ++n)                                              \
        acc[m][n] = __builtin_amdgcn_mfma_f32_16x16x32_bf16(af[m], bfv[n], acc[m][n], 0, 0, 0); \
  } while (0)

#define WBAR(n) asm volatile("s_waitcnt vmcnt(" #n ")\n\ts_barrier" ::: "memory")

  // prologue: tiles 0,1 in flight (4 loads/thread)
  STAGE(0, 0);
  STAGE(1, 32);

  // 48 K-tiles total. Main loop computes 0..45, staging tt+2 after barrier.
  int bufc = 0;
  #pragma unroll 3
  for (int tt = 0; tt < 46; ++tt) {
    WBAR(2);                             // tile tt landed; tt+1 stays in flight
    int bufn = bufc + 2; if (bufn >= 3) bufn -= 3;
    STAGE(bufn, (tt + 2) * 32);          // in flight across compute + barrier
    COMPUTE(bufc);
    bufc = (bufc == 2) ? 0 : bufc + 1;
  }
  WBAR(2);  COMPUTE(bufc);               // tile 46
  bufc = (bufc == 2) ? 0 : bufc + 1;
  WBAR(0);  COMPUTE(bufc);               // tile 47

  // epilogue: + b1, cast bf16, store
  int orow = bm * 64 + wm * 32 + (lane >> 4) * 4;
  int ocol = bn * 64 + wn * 32 + (lane & 15);
  #pragma unroll
  for (int m = 0; m < 2; ++m)
    #pragma unroll
    for (int n = 0; n < 2; ++n) {
      int col = ocol + n * 16;
      float bv = b1[col];
      #pragma unroll
      for (int r = 0; r < 4; ++r) {
        Hout[(orow + m * 16 + r) * HDIM + col] = f2bf(acc[m][n][r] + bv);
      }
    }
#undef STAGE
#undef COMPUTE
#undef WBAR
}

// Kernel 5: LayerNorm + exact GELU + W2 matvec (9) + 0.5/0.5 combine with base
__global__ __launch_bounds__(192) void k_ln(const unsigned short* __restrict__ Hin,
                                            const float* __restrict__ gamma,
                                            const float* __restrict__ beta,
                                            const float* __restrict__ W2,
                                            const float* __restrict__ b2,
                                            const float* __restrict__ base,
                                            float* __restrict__ out) {
  __shared__ float redS[3], redQ[3], redp[3][LOUT];
  int row = blockIdx.x;
  int t = threadIdx.x;
  int lane = t & 63, wave = t >> 6;
  const ushort4 hv = *(const ushort4*)(Hin + row * HDIM + t * 4);
  const float vv[4] = { bf2f(hv.x), bf2f(hv.y), bf2f(hv.z), bf2f(hv.w) };
  float s1 = vv[0] + vv[1] + vv[2] + vv[3];
  float s2 = vv[0]*vv[0] + vv[1]*vv[1] + vv[2]*vv[2] + vv[3]*vv[3];
  #pragma unroll
  for (int m = 1; m < 64; m <<= 1) { s1 += __shfl_xor(s1, m); s2 += __shfl_xor(s2, m); }
  if (lane == 0) { redS[wave] = s1; redQ[wave] = s2; }
  __syncthreads();
  s1 = redS[0] + redS[1] + redS[2];
  s2 = redQ[0] + redQ[1] + redQ[2];
  float mu = s1 * (1.f / HDIM);
  float var = s2 * (1.f / HDIM) - mu * mu;
  float rstd = rsqrtf(var + 1e-5f);
  const float4 g4 = *(const float4*)(gamma + t * 4);
  const float4 be4 = *(const float4*)(beta + t * 4);
  const float gv[4] = { g4.x, g4.y, g4.z, g4.w };
  const float bv[4] = { be4.x, be4.y, be4.z, be4.w };
  float p[LOUT] = {};
  #pragma unroll
  for (int j = 0; j < 4; ++j) {
    float g = (vv[j] - mu) * rstd * gv[j] + bv[j];
    float gg = 0.5f * g * (1.f + erff(g * 0.70710678118654752f));
    const float* wrow = W2 + (t * 4 + j) * LOUT;
    #pragma unroll
    for (int l = 0; l < LOUT; ++l) p[l] += gg * wrow[l];
  }
  #pragma unroll
  for (int l = 0; l < LOUT; ++l)
    #pragma unroll
    for (int m = 1; m < 64; m <<= 1) p[l] += __shfl_xor(p[l], m);
  if (lane == 0) {
    #pragma unroll
    for (int l = 0; l < LOUT; ++l) redp[wave][l] = p[l];
  }
  __syncthreads();
  if (t < LOUT) {
    float cl = redp[0][t] + redp[1][t] + redp[2][t] + b2[t];
    out[row * LOUT + t] = 0.5f * base[row * LOUT + t] + 0.5f * cl;
  }
}

extern "C" void kernel_launch(void* const* d_in, const int* in_sizes, int n_in,
                              void* d_out, int out_size, void* d_ws, size_t ws_size,
                              hipStream_t stream) {
  const float* x     = (const float*)d_in[0];
  const float* Wc    = (const float*)d_in[1];
  const float* bc    = (const float*)d_in[2];
  const float* wa    = (const float*)d_in[3];
  const float* ba    = (const float*)d_in[4];
  const float* W1    = (const float*)d_in[5];
  const float* b1    = (const float*)d_in[6];
  const float* gamma = (const float*)d_in[7];
  const float* beta  = (const float*)d_in[8];
  const float* W2    = (const float*)d_in[9];
  const float* b2    = (const float*)d_in[10];
  float* out = (float*)d_out;

  char* ws = (char*)d_ws;
  unsigned short* xc  = (unsigned short*)(ws);             // 8192*1536*2  = 25,165,824
  unsigned short* w1t = (unsigned short*)(ws + 25165824);  // 768*1536*2   =  2,359,296
  float* scores       = (float*)(ws + 27525120);           // 8192*4       =     32,768
  float* base         = (float*)(ws + 27557888);           // 8192*9*4     =    294,912
  unsigned short* hbuf = (unsigned short*)(ws + 27852800); // 8192*768*2   = 12,582,912

  k_prep_w1t<<<dim3(1152), dim3(256), 0, stream>>>(W1, w1t);
  k_prep    <<<dim3(8192), dim3(192), 0, stream>>>(x, wa, ba, Wc, bc, xc, scores, base);
  k_ctx     <<<dim3(8192), dim3(192), 0, stream>>>(scores, xc);
  k_gemm    <<<dim3(1536), dim3(256), 0, stream>>>(xc, w1t, b1, hbuf);
  k_ln      <<<dim3(8192), dim3(192), 0, stream>>>(hbuf, gamma, beta, W2, b2, base, out);
}

// Round 9
// 174.707 us; speedup vs baseline: 1.0750x; 1.0606x over previous
//
#include <hip/hip_runtime.h>
#include <hip/hip_bf16.h>
#include <math.h>

#define S_LEN 2048
#define BATCH 4
#define HDIM 768
#define LOUT 9
#define NROWS (BATCH*S_LEN)
#define K2H 1536
#define KHALF 768
#define WIN 11
#define NEG_INF_F (-1e30f)

typedef __attribute__((ext_vector_type(4))) float f32x4;
typedef __attribute__((ext_vector_type(8))) short bf16x8;

static __device__ __forceinline__ void async_ld16(const void* g, void* l) {
  __builtin_amdgcn_global_load_lds((const __attribute__((address_space(1))) void*)g,
                                   (__attribute__((address_space(3))) void*)l, 16, 0, 0);
}

static __device__ __forceinline__ unsigned short f2bf(float f) {
  union { float f; unsigned int u; } v; v.f = f;
  unsigned int u = v.u;
  unsigned int r = (u + 0x7fffu + ((u >> 16) & 1u)) >> 16;
  return (unsigned short)r;
}

static __device__ __forceinline__ float bf2f(unsigned short h) {
  union { unsigned int u; float f; } v; v.u = ((unsigned int)h) << 16;
  return v.f;
}

// Kernel 1: W1 [1536][768] fp32 -> W1t [768][1536] bf16 (LDS-tiled transpose)
__global__ __launch_bounds__(256) void k_prep_w1t(const float* __restrict__ W1,
                                                  unsigned short* __restrict__ W1t) {
  __shared__ float tile[32][33];
  int bk = blockIdx.x % 48;
  int bn = blockIdx.x / 48;
  int tc = threadIdx.x % 32;
  int tr = threadIdx.x / 32;
  #pragma unroll
  for (int i = 0; i < 32; i += 8) {
    tile[tr + i][tc] = W1[(bk*32 + tr + i) * HDIM + bn*32 + tc];
  }
  __syncthreads();
  #pragma unroll
  for (int i = 0; i < 32; i += 8) {
    W1t[(bn*32 + tr + i) * K2H + bk*32 + tc] = f2bf(tile[tc][tr + i]);
  }
}

// Kernel 2: one pass over fp32 x per row —
//   x -> bf16 first half of xc, score = x·wa+ba, base logits = x·Wc+bc.
__global__ __launch_bounds__(192) void k_prep(const float* __restrict__ x,
                                              const float* __restrict__ wa,
                                              const float* __restrict__ ba,
                                              const float* __restrict__ Wc,
                                              const float* __restrict__ bc,
                                              unsigned short* __restrict__ xc,
                                              float* __restrict__ scores,
                                              float* __restrict__ base) {
  __shared__ float red[3][LOUT + 1];
  int bid = blockIdx.x;
  int row = (bid & 7) * 1024 + (bid >> 3);
  int t = threadIdx.x;
  int lane = t & 63, wave = t >> 6;
  const float4 v = *(const float4*)(x + row * HDIM + t * 4);
  const float4 w = *(const float4*)(wa + t * 4);
  ushort4 o;
  o.x = f2bf(v.x); o.y = f2bf(v.y); o.z = f2bf(v.z); o.w = f2bf(v.w);
  *(ushort4*)(xc + row * K2H + t * 4) = o;

  float pv[LOUT + 1];
  pv[LOUT] = v.x * w.x + v.y * w.y + v.z * w.z + v.w * w.w;
  #pragma unroll
  for (int l = 0; l < LOUT; ++l) pv[l] = 0.f;
  const float xvv[4] = { v.x, v.y, v.z, v.w };
  #pragma unroll
  for (int j = 0; j < 4; ++j) {
    const float* wr = Wc + (t * 4 + j) * LOUT;
    #pragma unroll
    for (int l = 0; l < LOUT; ++l) pv[l] += xvv[j] * wr[l];
  }
  #pragma unroll
  for (int l = 0; l <= LOUT; ++l)
    #pragma unroll
    for (int m = 1; m < 64; m <<= 1) pv[l] += __shfl_xor(pv[l], m);
  if (lane == 0) {
    #pragma unroll
    for (int l = 0; l <= LOUT; ++l) red[wave][l] = pv[l];
  }
  __syncthreads();
  if (t < LOUT) {
    base[row * LOUT + t] = red[0][t] + red[1][t] + red[2][t] + bc[t];
  } else if (t == LOUT) {
    scores[row] = red[0][LOUT] + red[1][LOUT] + red[2][LOUT] + ba[0];
  }
}

// Kernel 3: window softmax (scores precomputed) + weighted ctx from bf16 xc
__global__ __launch_bounds__(192) void k_ctx(const float* __restrict__ scores,
                                             unsigned short* __restrict__ xc) {
  __shared__ float swin[WIN];
  int bid = blockIdx.x;
  int row = (bid & 7) * 1024 + (bid >> 3);
  int b = row >> 11, s = row & 2047;
  int t = threadIdx.x;
  if (t < WIN) {
    int j = s - 5 + t;
    bool valid = (j >= 0) && (j < S_LEN);
    int jc = valid ? j : (j < 0 ? 0 : S_LEN - 1);
    swin[t] = valid ? scores[b * S_LEN + jc] : NEG_INF_F;
  }
  __syncthreads();
  float mx = swin[0];
  #pragma unroll
  for (int w = 1; w < WIN; ++w) mx = fmaxf(mx, swin[w]);
  float es[WIN], ssum = 0.f;
  #pragma unroll
  for (int w = 0; w < WIN; ++w) {
    float sv = swin[w];
    es[w] = (sv > -1e29f) ? __expf(sv - mx) : 0.f;
    ssum += es[w];
  }
  float inv = 1.f / ssum;
  float c0 = 0.f, c1 = 0.f, c2 = 0.f, c3 = 0.f;
  #pragma unroll
  for (int w = 0; w < WIN; ++w) {
    float aw = es[w] * inv;
    int j = s - 5 + w;
    int jc = (j < 0) ? 0 : ((j >= S_LEN) ? S_LEN - 1 : j);
    const ushort4 uv = *(const ushort4*)(xc + (((long)b * S_LEN + jc) * K2H) + t * 4);
    c0 += aw * bf2f(uv.x);
    c1 += aw * bf2f(uv.y);
    c2 += aw * bf2f(uv.z);
    c3 += aw * bf2f(uv.w);
  }
  ushort4 o;
  o.x = f2bf(c0); o.y = f2bf(c1); o.z = f2bf(c2); o.w = f2bf(c3);
  *(ushort4*)(xc + row * K2H + HDIM + t * 4) = o;
}

// Kernel 4: SPLIT-K GEMM. h_partial[kh] = xc[:, kh*768:(kh+1)*768] @ W1t^T
// 128x128 tile, 4 waves each 64x64 (16 MFMA : 8 ds_read = 2:1), BK=32,
// 24 K-iters, grid 384*2 = 768 (3 blocks/CU, 12 waves/CU).
// R5-proven 2-phase dbuf + __syncthreads; 4-slot XOR swizzle (2-way = free).
// fp32 partial outputs (no bias; k_ln sums p0+p1+b1).
__global__ __launch_bounds__(256, 3) void k_gemm(const unsigned short* __restrict__ A,
                                                 const unsigned short* __restrict__ Bt,
                                                 float* __restrict__ Hout) {
  __shared__ unsigned short As[2][128 * 32];  // 8 KB x2
  __shared__ unsigned short Bs[2][128 * 32];  // 8 KB x2  -> 32 KB
  int bid = blockIdx.x;
  int obid = (bid & 7) * 96 + (bid >> 3);     // XCD-bijective (768%8==0)
  int kh = obid / 384;                        // K-half: XCDs 0-3 -> 0, 4-7 -> 1
  int mt = obid % 384;
  int bm = mt / 6, bn = mt % 6;
  int t = threadIdx.x;
  int lane = t & 63, wave = t >> 6;
  int wm = wave >> 1, wn = wave & 1;

  // --- staging: wave covers 16 rows per call; lane -> row wave*16+(lane>>2),
  // slot lane&3. Pre-swizzled source slot (rule #21): phys slot p of row r
  // holds global slot p ^ f(r), f(r) = (r ^ (r>>2)) & 3.
  int rowc = lane >> 2;                       // 0..15
  int fST = ((lane >> 2) ^ (lane >> 4)) & 3;  // f(local row), same for all calls
  int sST = (lane & 3) ^ fST;
  const unsigned short* gA0 = A  + (long)(bm * 128 + wave * 16 + rowc) * K2H + kh * KHALF + sST * 8;
  const unsigned short* gB0 = Bt + (long)(bn * 128 + wave * 16 + rowc) * K2H + kh * KHALF + sST * 8;

  // --- read side: f(rl) for rl = base + (lane&15); slR = phys slot of k-group
  int fR = ((lane & 3) ^ ((lane >> 2) & 3)) & 3;
  int slR = ((lane >> 4) ^ fR) & 3;
  int arow = wm * 64 + (lane & 15);
  int brow = wn * 64 + (lane & 15);

  f32x4 acc[4][4] = {};

#define STAGE(buf, kt) do {                                                    \
    async_ld16(gA0 + (kt),            &As[buf][(wave * 16) * 32]);             \
    async_ld16(gA0 + 64 * K2H + (kt), &As[buf][(64 + wave * 16) * 32]);        \
    async_ld16(gB0 + (kt),            &Bs[buf][(wave * 16) * 32]);             \
    async_ld16(gB0 + 64 * K2H + (kt), &Bs[buf][(64 + wave * 16) * 32]);        \
  } while (0)

#define COMPUTE(buf) do {                                                      \
    bf16x8 af[4], bfv[4];                                                      \
    _Pragma("unroll")                                                          \
    for (int m = 0; m < 4; ++m)                                                \
      af[m] = *(const bf16x8*)(&As[buf][(arow + m * 16) * 32 + slR * 8]);      \
    _Pragma("unroll")                                                          \
    for (int n = 0; n < 4; ++n)                                                \
      bfv[n] = *(const bf16x8*)(&Bs[buf][(brow + n * 16) * 32 + slR * 8]);     \
    _Pragma("unroll")                                                          \
    for (int m = 0; m < 4; ++m)                                                \
      _Pragma("unroll")                                                        \
      for (int n = 0; n < 4; ++n)                                              \
        acc[m][n] = __builtin_amdgcn_mfma_f32_16x16x32_bf16(af[m], bfv[n], acc[m][n], 0, 0, 0); \
  } while (0)

  STAGE(0, 0);
  __syncthreads();
  int cur = 0;
  #pragma unroll 1
  for (int tt = 0; tt < 23; ++tt) {
    STAGE(cur ^ 1, (tt + 1) * 32);   // in flight during COMPUTE
    COMPUTE(cur);
    __syncthreads();                  // drains stage; next buf ready
    cur ^= 1;
  }
  COMPUTE(cur);

  float* Hp = Hout + (long)kh * NROWS * HDIM;
  int orow = bm * 128 + wm * 64 + (lane >> 4) * 4;
  int ocol = bn * 128 + wn * 64 + (lane & 15);
  #pragma unroll
  for (int m = 0; m < 4; ++m)
    #pragma unroll
    for (int n = 0; n < 4; ++n) {
      int col = ocol + n * 16;
      #pragma unroll
      for (int r = 0; r < 4; ++r) {
        Hp[(long)(orow + m * 16 + r) * HDIM + col] = acc[m][n][r];
      }
    }
#undef STAGE
#undef COMPUTE
}

// Kernel 5: sum split-K partials + b1, LayerNorm, exact GELU, W2 matvec,
// 0.5/0.5 combine with base.
__global__ __launch_bounds__(192) void k_ln(const float* __restrict__ H0,
                                            const float* __restrict__ H1,
                                            const float* __restrict__ b1,
                                            const float* __restrict__ gamma,
                                            const float* __restrict__ beta,
                                            const float* __restrict__ W2,
                                            const float* __restrict__ b2,
                                            const float* __restrict__ base,
                                            float* __restrict__ out) {
  __shared__ float redS[3], redQ[3], redp[3][LOUT];
  int row = blockIdx.x;
  int t = threadIdx.x;
  int lane = t & 63, wave = t >> 6;
  const float4 p0 = *(const float4*)(H0 + (long)row * HDIM + t * 4);
  const float4 p1 = *(const float4*)(H1 + (long)row * HDIM + t * 4);
  const float4 b14 = *(const float4*)(b1 + t * 4);
  const float vv[4] = { p0.x + p1.x + b14.x, p0.y + p1.y + b14.y,
                        p0.z + p1.z + b14.z, p0.w + p1.w + b14.w };
  float s1 = vv[0] + vv[1] + vv[2] + vv[3];
  float s2 = vv[0]*vv[0] + vv[1]*vv[1] + vv[2]*vv[2] + vv[3]*vv[3];
  #pragma unroll
  for (int m = 1; m < 64; m <<= 1) { s1 += __shfl_xor(s1, m); s2 += __shfl_xor(s2, m); }
  if (lane == 0) { redS[wave] = s1; redQ[wave] = s2; }
  __syncthreads();
  s1 = redS[0] + redS[1] + redS[2];
  s2 = redQ[0] + redQ[1] + redQ[2];
  float mu = s1 * (1.f / HDIM);
  float var = s2 * (1.f / HDIM) - mu * mu;
  float rstd = rsqrtf(var + 1e-5f);
  const float4 g4 = *(const float4*)(gamma + t * 4);
  const float4 be4 = *(const float4*)(beta + t * 4);
  const float gv[4] = { g4.x, g4.y, g4.z, g4.w };
  const float bv[4] = { be4.x, be4.y, be4.z, be4.w };
  float p[LOUT] = {};
  #pragma unroll
  for (int j = 0; j < 4; ++j) {
    float g = (vv[j] - mu) * rstd * gv[j] + bv[j];
    float gg = 0.5f * g * (1.f + erff(g * 0.70710678118654752f));
    const float* wrow = W2 + (t * 4 + j) * LOUT;
    #pragma unroll
    for (int l = 0; l < LOUT; ++l) p[l] += gg * wrow[l];
  }
  #pragma unroll
  for (int l = 0; l < LOUT; ++l)
    #pragma unroll
    for (int m = 1; m < 64; m <<= 1) p[l] += __shfl_xor(p[l], m);
  if (lane == 0) {
    #pragma unroll
    for (int l = 0; l < LOUT; ++l) redp[wave][l] = p[l];
  }
  __syncthreads();
  if (t < LOUT) {
    float cl = redp[0][t] + redp[1][t] + redp[2][t] + b2[t];
    out[row * LOUT + t] = 0.5f * base[row * LOUT + t] + 0.5f * cl;
  }
}

extern "C" void kernel_launch(void* const* d_in, const int* in_sizes, int n_in,
                              void* d_out, int out_size, void* d_ws, size_t ws_size,
                              hipStream_t stream) {
  const float* x     = (const float*)d_in[0];
  const float* Wc    = (const float*)d_in[1];
  const float* bc    = (const float*)d_in[2];
  const float* wa    = (const float*)d_in[3];
  const float* ba    = (const float*)d_in[4];
  const float* W1    = (const float*)d_in[5];
  const float* b1    = (const float*)d_in[6];
  const float* gamma = (const float*)d_in[7];
  const float* beta  = (const float*)d_in[8];
  const float* W2    = (const float*)d_in[9];
  const float* b2    = (const float*)d_in[10];
  float* out = (float*)d_out;

  char* ws = (char*)d_ws;
  unsigned short* xc  = (unsigned short*)(ws);             // 8192*1536*2  = 25,165,824
  unsigned short* w1t = (unsigned short*)(ws + 25165824);  // 768*1536*2   =  2,359,296
  float* scores       = (float*)(ws + 27525120);           // 8192*4       =     32,768
  float* base         = (float*)(ws + 27557888);           // 8192*9*4     =    294,912
  float* hbuf         = (float*)(ws + 27852800);           // 2*8192*768*4 = 50,331,648

  k_prep_w1t<<<dim3(1152), dim3(256), 0, stream>>>(W1, w1t);
  k_prep    <<<dim3(8192), dim3(192), 0, stream>>>(x, wa, ba, Wc, bc, xc, scores, base);
  k_ctx     <<<dim3(8192), dim3(192), 0, stream>>>(scores, xc);
  k_gemm    <<<dim3(768),  dim3(256), 0, stream>>>(xc, w1t, hbuf);
  k_ln      <<<dim3(8192), dim3(192), 0, stream>>>(hbuf, hbuf + (long)NROWS * HDIM, b1,
                                                   gamma, beta, W2, b2, base, out);
}

// Round 10
// 174.285 us; speedup vs baseline: 1.0776x; 1.0024x over previous
//
#include <hip/hip_runtime.h>
#include <hip/hip_bf16.h>
#include <math.h>

#define S_LEN 2048
#define BATCH 4
#define HDIM 768
#define LOUT 9
#define NROWS (BATCH*S_LEN)
#define K2H 1536
#define KHALF 768
#define WIN 11
#define NEG_INF_F (-1e30f)

typedef __attribute__((ext_vector_type(4))) float f32x4;
typedef __attribute__((ext_vector_type(8))) short bf16x8;

static __device__ __forceinline__ void async_ld16(const void* g, void* l) {
  __builtin_amdgcn_global_load_lds((const __attribute__((address_space(1))) void*)g,
                                   (__attribute__((address_space(3))) void*)l, 16, 0, 0);
}

static __device__ __forceinline__ unsigned short f2bf(float f) {
  union { float f; unsigned int u; } v; v.f = f;
  unsigned int u = v.u;
  unsigned int r = (u + 0x7fffu + ((u >> 16) & 1u)) >> 16;
  return (unsigned short)r;
}

static __device__ __forceinline__ float bf2f(unsigned short h) {
  union { unsigned int u; float f; } v; v.u = ((unsigned int)h) << 16;
  return v.f;
}

// Kernel 1: W1 [1536][768] fp32 -> W1t [768][1536] bf16 (LDS-tiled transpose)
__global__ __launch_bounds__(256) void k_prep_w1t(const float* __restrict__ W1,
                                                  unsigned short* __restrict__ W1t) {
  __shared__ float tile[32][33];
  int bk = blockIdx.x % 48;
  int bn = blockIdx.x / 48;
  int tc = threadIdx.x % 32;
  int tr = threadIdx.x / 32;
  #pragma unroll
  for (int i = 0; i < 32; i += 8) {
    tile[tr + i][tc] = W1[(bk*32 + tr + i) * HDIM + bn*32 + tc];
  }
  __syncthreads();
  #pragma unroll
  for (int i = 0; i < 32; i += 8) {
    W1t[(bn*32 + tr + i) * K2H + bk*32 + tc] = f2bf(tile[tc][tr + i]);
  }
}

// Kernel 2: one pass over fp32 x per row —
//   x -> bf16 first half of xc, score = x·wa+ba, base logits = x·Wc+bc.
__global__ __launch_bounds__(192) void k_prep(const float* __restrict__ x,
                                              const float* __restrict__ wa,
                                              const float* __restrict__ ba,
                                              const float* __restrict__ Wc,
                                              const float* __restrict__ bc,
                                              unsigned short* __restrict__ xc,
                                              float* __restrict__ scores,
                                              float* __restrict__ base) {
  __shared__ float red[3][LOUT + 1];
  int bid = blockIdx.x;
  int row = (bid & 7) * 1024 + (bid >> 3);
  int t = threadIdx.x;
  int lane = t & 63, wave = t >> 6;
  const float4 v = *(const float4*)(x + row * HDIM + t * 4);
  const float4 w = *(const float4*)(wa + t * 4);
  ushort4 o;
  o.x = f2bf(v.x); o.y = f2bf(v.y); o.z = f2bf(v.z); o.w = f2bf(v.w);
  *(ushort4*)(xc + row * K2H + t * 4) = o;

  float pv[LOUT + 1];
  pv[LOUT] = v.x * w.x + v.y * w.y + v.z * w.z + v.w * w.w;
  #pragma unroll
  for (int l = 0; l < LOUT; ++l) pv[l] = 0.f;
  const float xvv[4] = { v.x, v.y, v.z, v.w };
  #pragma unroll
  for (int j = 0; j < 4; ++j) {
    const float* wr = Wc + (t * 4 + j) * LOUT;
    #pragma unroll
    for (int l = 0; l < LOUT; ++l) pv[l] += xvv[j] * wr[l];
  }
  #pragma unroll
  for (int l = 0; l <= LOUT; ++l)
    #pragma unroll
    for (int m = 1; m < 64; m <<= 1) pv[l] += __shfl_xor(pv[l], m);
  if (lane == 0) {
    #pragma unroll
    for (int l = 0; l <= LOUT; ++l) red[wave][l] = pv[l];
  }
  __syncthreads();
  if (t < LOUT) {
    base[row * LOUT + t] = red[0][t] + red[1][t] + red[2][t] + bc[t];
  } else if (t == LOUT) {
    scores[row] = red[0][LOUT] + red[1][LOUT] + red[2][LOUT] + ba[0];
  }
}

// Kernel 3: window softmax (scores precomputed) + weighted ctx from bf16 xc
__global__ __launch_bounds__(192) void k_ctx(const float* __restrict__ scores,
                                             unsigned short* __restrict__ xc) {
  __shared__ float swin[WIN];
  int bid = blockIdx.x;
  int row = (bid & 7) * 1024 + (bid >> 3);
  int b = row >> 11, s = row & 2047;
  int t = threadIdx.x;
  if (t < WIN) {
    int j = s - 5 + t;
    bool valid = (j >= 0) && (j < S_LEN);
    int jc = valid ? j : (j < 0 ? 0 : S_LEN - 1);
    swin[t] = valid ? scores[b * S_LEN + jc] : NEG_INF_F;
  }
  __syncthreads();
  float mx = swin[0];
  #pragma unroll
  for (int w = 1; w < WIN; ++w) mx = fmaxf(mx, swin[w]);
  float es[WIN], ssum = 0.f;
  #pragma unroll
  for (int w = 0; w < WIN; ++w) {
    float sv = swin[w];
    es[w] = (sv > -1e29f) ? __expf(sv - mx) : 0.f;
    ssum += es[w];
  }
  float inv = 1.f / ssum;
  float c0 = 0.f, c1 = 0.f, c2 = 0.f, c3 = 0.f;
  #pragma unroll
  for (int w = 0; w < WIN; ++w) {
    float aw = es[w] * inv;
    int j = s - 5 + w;
    int jc = (j < 0) ? 0 : ((j >= S_LEN) ? S_LEN - 1 : j);
    const ushort4 uv = *(const ushort4*)(xc + (((long)b * S_LEN + jc) * K2H) + t * 4);
    c0 += aw * bf2f(uv.x);
    c1 += aw * bf2f(uv.y);
    c2 += aw * bf2f(uv.z);
    c3 += aw * bf2f(uv.w);
  }
  ushort4 o;
  o.x = f2bf(c0); o.y = f2bf(c1); o.z = f2bf(c2); o.w = f2bf(c3);
  *(ushort4*)(xc + row * K2H + HDIM + t * 4) = o;
}

// Kernel 4: SPLIT-K GEMM. h_partial[kh] = xc[:, kh*768:(kh+1)*768] @ W1t^T
// 128x128 tile, 4 waves each 64x64 (16 MFMA : 8 ds_read = 2:1), BK=32,
// 24 K-iters, grid 384*2 = 768 (3 blocks/CU, 12 waves/CU).
// 2-phase dbuf + __syncthreads; 4-slot XOR swizzle. BF16 partial outputs.
__global__ __launch_bounds__(256, 3) void k_gemm(const unsigned short* __restrict__ A,
                                                 const unsigned short* __restrict__ Bt,
                                                 unsigned short* __restrict__ Hout) {
  __shared__ unsigned short As[2][128 * 32];  // 8 KB x2
  __shared__ unsigned short Bs[2][128 * 32];  // 8 KB x2  -> 32 KB
  int bid = blockIdx.x;
  int obid = (bid & 7) * 96 + (bid >> 3);     // XCD-bijective (768%8==0)
  int kh = obid / 384;                        // K-half: XCDs 0-3 -> 0, 4-7 -> 1
  int mt = obid % 384;
  int bm = mt / 6, bn = mt % 6;
  int t = threadIdx.x;
  int lane = t & 63, wave = t >> 6;
  int wm = wave >> 1, wn = wave & 1;

  // staging: wave covers 16 rows/call; lane -> row wave*16+(lane>>2), slot lane&3.
  // Pre-swizzled source slot (rule #21): phys slot p of row r holds p ^ f(r),
  // f(r) = (r ^ (r>>2)) & 3.
  int rowc = lane >> 2;
  int fST = ((lane >> 2) ^ (lane >> 4)) & 3;
  int sST = (lane & 3) ^ fST;
  const unsigned short* gA0 = A  + (long)(bm * 128 + wave * 16 + rowc) * K2H + kh * KHALF + sST * 8;
  const unsigned short* gB0 = Bt + (long)(bn * 128 + wave * 16 + rowc) * K2H + kh * KHALF + sST * 8;

  // read side
  int fR = ((lane & 3) ^ ((lane >> 2) & 3)) & 3;
  int slR = ((lane >> 4) ^ fR) & 3;
  int arow = wm * 64 + (lane & 15);
  int brow = wn * 64 + (lane & 15);

  f32x4 acc[4][4] = {};

#define STAGE(buf, kt) do {                                                    \
    async_ld16(gA0 + (kt),            &As[buf][(wave * 16) * 32]);             \
    async_ld16(gA0 + 64 * K2H + (kt), &As[buf][(64 + wave * 16) * 32]);        \
    async_ld16(gB0 + (kt),            &Bs[buf][(wave * 16) * 32]);             \
    async_ld16(gB0 + 64 * K2H + (kt), &Bs[buf][(64 + wave * 16) * 32]);        \
  } while (0)

#define COMPUTE(buf) do {                                                      \
    bf16x8 af[4], bfv[4];                                                      \
    _Pragma("unroll")                                                          \
    for (int m = 0; m < 4; ++m)                                                \
      af[m] = *(const bf16x8*)(&As[buf][(arow + m * 16) * 32 + slR * 8]);      \
    _Pragma("unroll")                                                          \
    for (int n = 0; n < 4; ++n)                                                \
      bfv[n] = *(const bf16x8*)(&Bs[buf][(brow + n * 16) * 32 + slR * 8]);     \
    _Pragma("unroll")                                                          \
    for (int m = 0; m < 4; ++m)                                                \
      _Pragma("unroll")                                                        \
      for (int n = 0; n < 4; ++n)                                              \
        acc[m][n] = __builtin_amdgcn_mfma_f32_16x16x32_bf16(af[m], bfv[n], acc[m][n], 0, 0, 0); \
  } while (0)

  STAGE(0, 0);
  __syncthreads();
  int cur = 0;
  #pragma unroll 1
  for (int tt = 0; tt < 23; ++tt) {
    STAGE(cur ^ 1, (tt + 1) * 32);   // in flight during COMPUTE
    COMPUTE(cur);
    __syncthreads();
    cur ^= 1;
  }
  COMPUTE(cur);

  unsigned short* Hp = Hout + (long)kh * NROWS * HDIM;
  int orow = bm * 128 + wm * 64 + (lane >> 4) * 4;
  int ocol = bn * 128 + wn * 64 + (lane & 15);
  #pragma unroll
  for (int m = 0; m < 4; ++m)
    #pragma unroll
    for (int n = 0; n < 4; ++n) {
      int col = ocol + n * 16;
      #pragma unroll
      for (int r = 0; r < 4; ++r) {
        Hp[(long)(orow + m * 16 + r) * HDIM + col] = f2bf(acc[m][n][r]);
      }
    }
#undef STAGE
#undef COMPUTE
}

// Kernel 5: sum bf16 split-K partials + b1, LayerNorm, exact GELU, W2 matvec,
// 0.5/0.5 combine with base.
__global__ __launch_bounds__(192) void k_ln(const unsigned short* __restrict__ H0,
                                            const unsigned short* __restrict__ H1,
                                            const float* __restrict__ b1,
                                            const float* __restrict__ gamma,
                                            const float* __restrict__ beta,
                                            const float* __restrict__ W2,
                                            const float* __restrict__ b2,
                                            const float* __restrict__ base,
                                            float* __restrict__ out) {
  __shared__ float redS[3], redQ[3], redp[3][LOUT];
  int row = blockIdx.x;
  int t = threadIdx.x;
  int lane = t & 63, wave = t >> 6;
  const ushort4 h0 = *(const ushort4*)(H0 + (long)row * HDIM + t * 4);
  const ushort4 h1 = *(const ushort4*)(H1 + (long)row * HDIM + t * 4);
  const float4 b14 = *(const float4*)(b1 + t * 4);
  const float vv[4] = { bf2f(h0.x) + bf2f(h1.x) + b14.x,
                        bf2f(h0.y) + bf2f(h1.y) + b14.y,
                        bf2f(h0.z) + bf2f(h1.z) + b14.z,
                        bf2f(h0.w) + bf2f(h1.w) + b14.w };
  float s1 = vv[0] + vv[1] + vv[2] + vv[3];
  float s2 = vv[0]*vv[0] + vv[1]*vv[1] + vv[2]*vv[2] + vv[3]*vv[3];
  #pragma unroll
  for (int m = 1; m < 64; m <<= 1) { s1 += __shfl_xor(s1, m); s2 += __shfl_xor(s2, m); }
  if (lane == 0) { redS[wave] = s1; redQ[wave] = s2; }
  __syncthreads();
  s1 = redS[0] + redS[1] + redS[2];
  s2 = redQ[0] + redQ[1] + redQ[2];
  float mu = s1 * (1.f / HDIM);
  float var = s2 * (1.f / HDIM) - mu * mu;
  float rstd = rsqrtf(var + 1e-5f);
  const float4 g4 = *(const float4*)(gamma + t * 4);
  const float4 be4 = *(const float4*)(beta + t * 4);
  const float gv[4] = { g4.x, g4.y, g4.z, g4.w };
  const float bvv[4] = { be4.x, be4.y, be4.z, be4.w };
  float p[LOUT] = {};
  #pragma unroll
  for (int j = 0; j < 4; ++j) {
    float g = (vv[j] - mu) * rstd * gv[j] + bvv[j];
    float gg = 0.5f * g * (1.f + erff(g * 0.70710678118654752f));
    const float* wrow = W2 + (t * 4 + j) * LOUT;
    #pragma unroll
    for (int l = 0; l < LOUT; ++l) p[l] += gg * wrow[l];
  }
  #pragma unroll
  for (int l = 0; l < LOUT; ++l)
    #pragma unroll
    for (int m = 1; m < 64; m <<= 1) p[l] += __shfl_xor(p[l], m);
  if (lane == 0) {
    #pragma unroll
    for (int l = 0; l < LOUT; ++l) redp[wave][l] = p[l];
  }
  __syncthreads();
  if (t < LOUT) {
    float cl = redp[0][t] + redp[1][t] + redp[2][t] + b2[t];
    out[row * LOUT + t] = 0.5f * base[row * LOUT + t] + 0.5f * cl;
  }
}

extern "C" void kernel_launch(void* const* d_in, const int* in_sizes, int n_in,
                              void* d_out, int out_size, void* d_ws, size_t ws_size,
                              hipStream_t stream) {
  const float* x     = (const float*)d_in[0];
  const float* Wc    = (const float*)d_in[1];
  const float* bc    = (const float*)d_in[2];
  const float* wa    = (const float*)d_in[3];
  const float* ba    = (const float*)d_in[4];
  const float* W1    = (const float*)d_in[5];
  const float* b1    = (const float*)d_in[6];
  const float* gamma = (const float*)d_in[7];
  const float* beta  = (const float*)d_in[8];
  const float* W2    = (const float*)d_in[9];
  const float* b2    = (const float*)d_in[10];
  float* out = (float*)d_out;

  char* ws = (char*)d_ws;
  unsigned short* xc   = (unsigned short*)(ws);             // 8192*1536*2  = 25,165,824
  unsigned short* w1t  = (unsigned short*)(ws + 25165824);  // 768*1536*2   =  2,359,296
  float* scores        = (float*)(ws + 27525120);           // 8192*4       =     32,768
  float* base          = (float*)(ws + 27557888);           // 8192*9*4     =    294,912
  unsigned short* hbuf = (unsigned short*)(ws + 27852800);  // 2*8192*768*2 = 25,165,824

  k_prep_w1t<<<dim3(1152), dim3(256), 0, stream>>>(W1, w1t);
  k_prep    <<<dim3(8192), dim3(192), 0, stream>>>(x, wa, ba, Wc, bc, xc, scores, base);
  k_ctx     <<<dim3(8192), dim3(192), 0, stream>>>(scores, xc);
  k_gemm    <<<dim3(768),  dim3(256), 0, stream>>>(xc, w1t, hbuf);
  k_ln      <<<dim3(8192), dim3(192), 0, stream>>>(hbuf, hbuf + (long)NROWS * HDIM, b1,
                                                   gamma, beta, W2, b2, base, out);
}

// Round 11
// 172.109 us; speedup vs baseline: 1.0912x; 1.0126x over previous
//
#include <hip/hip_runtime.h>
#include <hip/hip_bf16.h>
#include <math.h>

#define S_LEN 2048
#define BATCH 4
#define HDIM 768
#define LOUT 9
#define NROWS (BATCH*S_LEN)
#define K2H 1536
#define KHALF 768
#define WIN 11
#define NEG_INF_F (-1e30f)

typedef __attribute__((ext_vector_type(4))) float f32x4;
typedef __attribute__((ext_vector_type(8))) short bf16x8;

static __device__ __forceinline__ void async_ld16(const void* g, void* l) {
  __builtin_amdgcn_global_load_lds((const __attribute__((address_space(1))) void*)g,
                                   (__attribute__((address_space(3))) void*)l, 16, 0, 0);
}

static __device__ __forceinline__ unsigned short f2bf(float f) {
  union { float f; unsigned int u; } v; v.f = f;
  unsigned int u = v.u;
  unsigned int r = (u + 0x7fffu + ((u >> 16) & 1u)) >> 16;
  return (unsigned short)r;
}

static __device__ __forceinline__ float bf2f(unsigned short h) {
  union { unsigned int u; float f; } v; v.u = ((unsigned int)h) << 16;
  return v.f;
}

// Kernel A (fused): blocks 0..1151: W1 -> W1t bf16 transpose.
//                   blocks 1152+ : wave-per-row prep (x->bf16, score, base logits).
__global__ __launch_bounds__(256) void k_prep(const float* __restrict__ W1,
                                              unsigned short* __restrict__ W1t,
                                              const float* __restrict__ x,
                                              const float* __restrict__ wa,
                                              const float* __restrict__ ba,
                                              const float* __restrict__ Wc,
                                              const float* __restrict__ bc,
                                              unsigned short* __restrict__ xc,
                                              float* __restrict__ scores,
                                              float* __restrict__ base) {
  __shared__ float tile[32][33];
  if (blockIdx.x < 1152) {
    int bk = blockIdx.x % 48;
    int bn = blockIdx.x / 48;
    int tc = threadIdx.x % 32;
    int tr = threadIdx.x / 32;
    #pragma unroll
    for (int i = 0; i < 32; i += 8) {
      tile[tr + i][tc] = W1[(bk*32 + tr + i) * HDIM + bn*32 + tc];
    }
    __syncthreads();
    #pragma unroll
    for (int i = 0; i < 32; i += 8) {
      W1t[(bn*32 + tr + i) * K2H + bk*32 + tc] = f2bf(tile[tc][tr + i]);
    }
    return;
  }
  int bid = blockIdx.x - 1152;              // 0..2047
  int lane = threadIdx.x & 63, wave = threadIdx.x >> 6;
  int row = bid * 4 + wave;                 // one wave per row
  const float* xr = x + (long)row * HDIM + lane * 12;
  float xv[12];
  { const float4 a = *(const float4*)(xr);
    const float4 b4 = *(const float4*)(xr + 4);
    const float4 c4 = *(const float4*)(xr + 8);
    xv[0]=a.x; xv[1]=a.y; xv[2]=a.z; xv[3]=a.w;
    xv[4]=b4.x; xv[5]=b4.y; xv[6]=b4.z; xv[7]=b4.w;
    xv[8]=c4.x; xv[9]=c4.y; xv[10]=c4.z; xv[11]=c4.w; }
  // bf16 cast -> first half of xc
  unsigned short* dst = xc + (long)row * K2H + lane * 12;
  #pragma unroll
  for (int q = 0; q < 3; ++q) {
    ushort4 o;
    o.x = f2bf(xv[q*4+0]); o.y = f2bf(xv[q*4+1]);
    o.z = f2bf(xv[q*4+2]); o.w = f2bf(xv[q*4+3]);
    *(ushort4*)(dst + q*4) = o;
  }
  // score partial
  const float* war = wa + lane * 12;
  float sc = 0.f;
  #pragma unroll
  for (int q = 0; q < 3; ++q) {
    const float4 w4 = *(const float4*)(war + q*4);
    sc += xv[q*4+0]*w4.x + xv[q*4+1]*w4.y + xv[q*4+2]*w4.z + xv[q*4+3]*w4.w;
  }
  // base-logit partials: lane's 12 Wc rows are contiguous (432 B)
  const float* wcr = Wc + (long)lane * 12 * LOUT;
  float p[LOUT] = {};
  #pragma unroll
  for (int j = 0; j < 12; ++j) {
    const float xj = xv[j];
    #pragma unroll
    for (int l = 0; l < LOUT; ++l) p[l] += xj * wcr[j * LOUT + l];
  }
  // one butterfly set per ROW (not per thread-triple)
  #pragma unroll
  for (int m = 1; m < 64; m <<= 1) {
    sc += __shfl_xor(sc, m);
    #pragma unroll
    for (int l = 0; l < LOUT; ++l) p[l] += __shfl_xor(p[l], m);
  }
  if (lane == 0) {
    scores[row] = sc + ba[0];
    #pragma unroll
    for (int l = 0; l < LOUT; ++l) base[row * LOUT + l] = p[l] + bc[l];
  }
}

// Kernel B: wave-per-row window softmax + weighted ctx (no shuffles, no LDS)
__global__ __launch_bounds__(256) void k_ctx(const float* __restrict__ scores,
                                             unsigned short* __restrict__ xc) {
  int lane = threadIdx.x & 63, wave = threadIdx.x >> 6;
  int row = blockIdx.x * 4 + wave;
  int b = row >> 11, s = row & 2047;
  float sw[WIN];
  int jcs[WIN];
  #pragma unroll
  for (int w = 0; w < WIN; ++w) {
    int j = s - 5 + w;
    bool valid = (j >= 0) && (j < S_LEN);
    int jc = valid ? j : (j < 0 ? 0 : S_LEN - 1);
    jcs[w] = b * S_LEN + jc;
    sw[w] = valid ? scores[b * S_LEN + jc] : NEG_INF_F;
  }
  float mx = sw[0];
  #pragma unroll
  for (int w = 1; w < WIN; ++w) mx = fmaxf(mx, sw[w]);
  float es[WIN], ssum = 0.f;
  #pragma unroll
  for (int w = 0; w < WIN; ++w) {
    es[w] = (sw[w] > -1e29f) ? __expf(sw[w] - mx) : 0.f;
    ssum += es[w];
  }
  float inv = 1.f / ssum;
  float c[12] = {};
  #pragma unroll
  for (int w = 0; w < WIN; ++w) {
    float aw = es[w] * inv;
    const unsigned short* src = xc + (long)jcs[w] * K2H + lane * 12;
    #pragma unroll
    for (int q = 0; q < 3; ++q) {
      const ushort4 uv = *(const ushort4*)(src + q*4);
      c[q*4+0] += aw * bf2f(uv.x);
      c[q*4+1] += aw * bf2f(uv.y);
      c[q*4+2] += aw * bf2f(uv.z);
      c[q*4+3] += aw * bf2f(uv.w);
    }
  }
  unsigned short* dst = xc + (long)row * K2H + HDIM + lane * 12;
  #pragma unroll
  for (int q = 0; q < 3; ++q) {
    ushort4 o;
    o.x = f2bf(c[q*4+0]); o.y = f2bf(c[q*4+1]);
    o.z = f2bf(c[q*4+2]); o.w = f2bf(c[q*4+3]);
    *(ushort4*)(dst + q*4) = o;
  }
}

// Kernel C: SPLIT-K GEMM (unchanged from R9 — proven). h_partial[kh] bf16.
__global__ __launch_bounds__(256, 3) void k_gemm(const unsigned short* __restrict__ A,
                                                 const unsigned short* __restrict__ Bt,
                                                 unsigned short* __restrict__ Hout) {
  __shared__ unsigned short As[2][128 * 32];
  __shared__ unsigned short Bs[2][128 * 32];
  int bid = blockIdx.x;
  int obid = (bid & 7) * 96 + (bid >> 3);
  int kh = obid / 384;
  int mt = obid % 384;
  int bm = mt / 6, bn = mt % 6;
  int t = threadIdx.x;
  int lane = t & 63, wave = t >> 6;
  int wm = wave >> 1, wn = wave & 1;

  int rowc = lane >> 2;
  int fST = ((lane >> 2) ^ (lane >> 4)) & 3;
  int sST = (lane & 3) ^ fST;
  const unsigned short* gA0 = A  + (long)(bm * 128 + wave * 16 + rowc) * K2H + kh * KHALF + sST * 8;
  const unsigned short* gB0 = Bt + (long)(bn * 128 + wave * 16 + rowc) * K2H + kh * KHALF + sST * 8;

  int fR = ((lane & 3) ^ ((lane >> 2) & 3)) & 3;
  int slR = ((lane >> 4) ^ fR) & 3;
  int arow = wm * 64 + (lane & 15);
  int brow = wn * 64 + (lane & 15);

  f32x4 acc[4][4] = {};

#define STAGE(buf, kt) do {                                                    \
    async_ld16(gA0 + (kt),            &As[buf][(wave * 16) * 32]);             \
    async_ld16(gA0 + 64 * K2H + (kt), &As[buf][(64 + wave * 16) * 32]);        \
    async_ld16(gB0 + (kt),            &Bs[buf][(wave * 16) * 32]);             \
    async_ld16(gB0 + 64 * K2H + (kt), &Bs[buf][(64 + wave * 16) * 32]);        \
  } while (0)

#define COMPUTE(buf) do {                                                      \
    bf16x8 af[4], bfv[4];                                                      \
    _Pragma("unroll")                                                          \
    for (int m = 0; m < 4; ++m)                                                \
      af[m] = *(const bf16x8*)(&As[buf][(arow + m * 16) * 32 + slR * 8]);      \
    _Pragma("unroll")                                                          \
    for (int n = 0; n < 4; ++n)                                                \
      bfv[n] = *(const bf16x8*)(&Bs[buf][(brow + n * 16) * 32 + slR * 8]);     \
    _Pragma("unroll")                                                          \
    for (int m = 0; m < 4; ++m)                                                \
      _Pragma("unroll")                                                        \
      for (int n = 0; n < 4; ++n)                                              \
        acc[m][n] = __builtin_amdgcn_mfma_f32_16x16x32_bf16(af[m], bfv[n], acc[m][n], 0, 0, 0); \
  } while (0)

  STAGE(0, 0);
  __syncthreads();
  int cur = 0;
  #pragma unroll 1
  for (int tt = 0; tt < 23; ++tt) {
    STAGE(cur ^ 1, (tt + 1) * 32);
    COMPUTE(cur);
    __syncthreads();
    cur ^= 1;
  }
  COMPUTE(cur);

  unsigned short* Hp = Hout + (long)kh * NROWS * HDIM;
  int orow = bm * 128 + wm * 64 + (lane >> 4) * 4;
  int ocol = bn * 128 + wn * 64 + (lane & 15);
  #pragma unroll
  for (int m = 0; m < 4; ++m)
    #pragma unroll
    for (int n = 0; n < 4; ++n) {
      int col = ocol + n * 16;
      #pragma unroll
      for (int r = 0; r < 4; ++r) {
        Hp[(long)(orow + m * 16 + r) * HDIM + col] = f2bf(acc[m][n][r]);
      }
    }
#undef STAGE
#undef COMPUTE
}

// Kernel D: wave-per-row: sum bf16 partials + b1, LN, exact GELU, W2, combine.
__global__ __launch_bounds__(256) void k_ln(const unsigned short* __restrict__ H0,
                                            const unsigned short* __restrict__ H1,
                                            const float* __restrict__ b1,
                                            const float* __restrict__ gamma,
                                            const float* __restrict__ beta,
                                            const float* __restrict__ W2,
                                            const float* __restrict__ b2,
                                            const float* __restrict__ base,
                                            float* __restrict__ out) {
  int lane = threadIdx.x & 63, wave = threadIdx.x >> 6;
  int row = blockIdx.x * 4 + wave;
  const unsigned short* h0p = H0 + (long)row * HDIM + lane * 12;
  const unsigned short* h1p = H1 + (long)row * HDIM + lane * 12;
  const float* b1p = b1 + lane * 12;
  float vv[12];
  #pragma unroll
  for (int q = 0; q < 3; ++q) {
    const ushort4 a = *(const ushort4*)(h0p + q*4);
    const ushort4 b4 = *(const ushort4*)(h1p + q*4);
    const float4 bb = *(const float4*)(b1p + q*4);
    vv[q*4+0] = bf2f(a.x) + bf2f(b4.x) + bb.x;
    vv[q*4+1] = bf2f(a.y) + bf2f(b4.y) + bb.y;
    vv[q*4+2] = bf2f(a.z) + bf2f(b4.z) + bb.z;
    vv[q*4+3] = bf2f(a.w) + bf2f(b4.w) + bb.w;
  }
  float s1 = 0.f, s2 = 0.f;
  #pragma unroll
  for (int j = 0; j < 12; ++j) { s1 += vv[j]; s2 += vv[j] * vv[j]; }
  #pragma unroll
  for (int m = 1; m < 64; m <<= 1) { s1 += __shfl_xor(s1, m); s2 += __shfl_xor(s2, m); }
  float mu = s1 * (1.f / HDIM);
  float var = s2 * (1.f / HDIM) - mu * mu;
  float rstd = rsqrtf(var + 1e-5f);
  const float* gp = gamma + lane * 12;
  const float* bp = beta + lane * 12;
  const float* w2r = W2 + (long)lane * 12 * LOUT;
  float p[LOUT] = {};
  #pragma unroll
  for (int q = 0; q < 3; ++q) {
    const float4 g4 = *(const float4*)(gp + q*4);
    const float4 be4 = *(const float4*)(bp + q*4);
    const float gv[4] = { g4.x, g4.y, g4.z, g4.w };
    const float bvv[4] = { be4.x, be4.y, be4.z, be4.w };
    #pragma unroll
    for (int k = 0; k < 4; ++k) {
      int j = q*4 + k;
      float g = (vv[j] - mu) * rstd * gv[k] + bvv[k];
      float gg = 0.5f * g * (1.f + erff(g * 0.70710678118654752f));
      #pragma unroll
      for (int l = 0; l < LOUT; ++l) p[l] += gg * w2r[j * LOUT + l];
    }
  }
  #pragma unroll
  for (int m = 1; m < 64; m <<= 1)
    #pragma unroll
    for (int l = 0; l < LOUT; ++l) p[l] += __shfl_xor(p[l], m);
  if (lane == 0) {
    #pragma unroll
    for (int l = 0; l < LOUT; ++l) {
      out[row * LOUT + l] = 0.5f * base[row * LOUT + l] + 0.5f * (p[l] + b2[l]);
    }
  }
}

extern "C" void kernel_launch(void* const* d_in, const int* in_sizes, int n_in,
                              void* d_out, int out_size, void* d_ws, size_t ws_size,
                              hipStream_t stream) {
  const float* x     = (const float*)d_in[0];
  const float* Wc    = (const float*)d_in[1];
  const float* bc    = (const float*)d_in[2];
  const float* wa    = (const float*)d_in[3];
  const float* ba    = (const float*)d_in[4];
  const float* W1    = (const float*)d_in[5];
  const float* b1    = (const float*)d_in[6];
  const float* gamma = (const float*)d_in[7];
  const float* beta  = (const float*)d_in[8];
  const float* W2    = (const float*)d_in[9];
  const float* b2    = (const float*)d_in[10];
  float* out = (float*)d_out;

  char* ws = (char*)d_ws;
  unsigned short* xc   = (unsigned short*)(ws);             // 8192*1536*2  = 25,165,824
  unsigned short* w1t  = (unsigned short*)(ws + 25165824);  // 768*1536*2   =  2,359,296
  float* scores        = (float*)(ws + 27525120);           // 8192*4       =     32,768
  float* base          = (float*)(ws + 27557888);           // 8192*9*4     =    294,912
  unsigned short* hbuf = (unsigned short*)(ws + 27852800);  // 2*8192*768*2 = 25,165,824

  k_prep <<<dim3(1152 + 2048), dim3(256), 0, stream>>>(W1, w1t, x, wa, ba, Wc, bc,
                                                       xc, scores, base);
  k_ctx  <<<dim3(2048), dim3(256), 0, stream>>>(scores, xc);
  k_gemm <<<dim3(768),  dim3(256), 0, stream>>>(xc, w1t, hbuf);
  k_ln   <<<dim3(2048), dim3(256), 0, stream>>>(hbuf, hbuf + (long)NROWS * HDIM, b1,
                                                gamma, beta, W2, b2, base, out);
}